// Round 8
// baseline (274.665 us; speedup 1.0000x reference)
//
#include <hip/hip_runtime.h>

typedef __attribute__((ext_vector_type(8))) short short8;
typedef __attribute__((ext_vector_type(4))) float float4v;

#define D_MODEL 512
#define NUM_HEADS 8
#define DEPTH 64
#define SEQ 4096
#define BATCH 2
#define MROWS 8192
// 0.125 * log2(e): folded into Q projection so attn uses raw v_exp_f32 (exp2)
#define SCALE_Q 0.18033688011112043f

// swizzled short-index of 16B chunk c in row r of a 64-short-wide LDS tile
#define SW(r, c) (((r) * 64) + ((((c) ^ ((r) & 7))) * 8))
// 128-short-wide variant
#define SW128(n, c) (((n) * 128) + ((((c) ^ ((n) & 15))) * 8))

static __device__ __forceinline__ unsigned short f2bf(float f) {
  unsigned int u = __builtin_bit_cast(unsigned int, f);
  u += 0x7FFFu + ((u >> 16) & 1u); // RNE
  return (unsigned short)(u >> 16);
}
static __device__ __forceinline__ unsigned int pk2(float a, float b) {
  return (unsigned int)f2bf(a) | ((unsigned int)f2bf(b) << 16);
}
// fast pack: round-half-up (RNE except exact ties) + single v_perm_b32
static __device__ __forceinline__ unsigned int pk2f(float a, float b) {
  unsigned int ua = __builtin_bit_cast(unsigned int, a) + 0x8000u;
  unsigned int ub = __builtin_bit_cast(unsigned int, b) + 0x8000u;
  return __builtin_amdgcn_perm(ub, ua, 0x07060302u); // [b.3 b.2 a.3 a.2]
}
// convert 8 consecutive fp32 at p to short8 (RNE)
static __device__ __forceinline__ short8 cvt8(const float* p) {
  float4v f0 = *(const float4v*)p;
  float4v f1 = *(const float4v*)(p + 4);
  short8 s;
#pragma unroll
  for (int j = 0; j < 4; ++j) {
    s[j] = (short)f2bf(f0[j]);
    s[4 + j] = (short)f2bf(f1[j]);
  }
  return s;
}

// ---------------- 128x128-tile QKV projection (fp32 X, fp32 W inline) -------
// z=0: Q -> [b][h][s][d] bf16 scaled by SCALE_Q; z=1: K same unscaled;
// z=2: V -> [b][h][d][s] bf16 via LDS transpose.
struct QkvA {
  const float* X[3];
  const float* W[3];
  const float* bias[3];
  unsigned short* out[3];
};
__global__ __launch_bounds__(256) void gemm128_qkv(QkvA a) {
  __shared__ unsigned short smem[2 * 128 * 64];
  unsigned short* As = smem;
  unsigned short* Bs = smem + 128 * 64;
  const int z = blockIdx.z;
  const float* __restrict__ X = a.X[z];
  const float* __restrict__ W = a.W[z];
  const float* __restrict__ bias = a.bias[z];
  unsigned short* __restrict__ out = a.out[z];
  const int t = threadIdx.x;
  const int w = t >> 6, l = t & 63, lq = l >> 4, lm = l & 15;
  const int mq = (w & 1) * 64, nq = (w >> 1) * 64;
  const int mBase = blockIdx.x * 128, nBase = blockIdx.y * 128;
  float4v acc[4][4] = {};
  for (int kc = 0; kc < D_MODEL; kc += 64) {
    __syncthreads();
#pragma unroll
    for (int p = 0; p < 4; ++p) {
      int i = p * 256 + t, r = i >> 3, c = i & 7;
      *(short8*)&As[SW(r, c)] = cvt8(&X[(size_t)(mBase + r) * D_MODEL + kc + c * 8]);
      *(short8*)&Bs[SW(r, c)] = cvt8(&W[(size_t)(nBase + r) * D_MODEL + kc + c * 8]);
    }
    __syncthreads();
#pragma unroll
    for (int kk = 0; kk < 2; ++kk) {
      short8 av[4];
#pragma unroll
      for (int fm = 0; fm < 4; ++fm)
        av[fm] = *(const short8*)&As[SW(mq + fm * 16 + lm, kk * 4 + lq)];
#pragma unroll
      for (int fn = 0; fn < 4; ++fn) {
        short8 bv = *(const short8*)&Bs[SW(nq + fn * 16 + lm, kk * 4 + lq)];
#pragma unroll
        for (int fm = 0; fm < 4; ++fm)
          acc[fm][fn] = __builtin_amdgcn_mfma_f32_16x16x32_bf16(av[fm], bv, acc[fm][fn], 0, 0, 0);
      }
    }
  }
  if (z == 2) {
    __syncthreads(); // protect As/Bs reuse
    unsigned short* T = smem; // 128 x 128 shorts
#pragma unroll
    for (int fn = 0; fn < 4; ++fn) {
      int n = nq + fn * 16 + lm;
      float bv = bias[nBase + n];
#pragma unroll
      for (int fm = 0; fm < 4; ++fm) {
        int m0 = mq + fm * 16 + lq * 4;
        uint2 u;
        u.x = pk2(acc[fm][fn][0] + bv, acc[fm][fn][1] + bv);
        u.y = pk2(acc[fm][fn][2] + bv, acc[fm][fn][3] + bv);
        *(uint2*)&T[SW128(n, m0 >> 3) + (lq & 1) * 4] = u;
      }
    }
    __syncthreads();
    const int bb = mBase >> 12, s0 = mBase & 4095;
#pragma unroll
    for (int p = 0; p < 8; ++p) {
      int i = p * 256 + t, n = i >> 4, cm = i & 15;
      int gn = nBase + n, h = gn >> 6, d = gn & 63;
      *(short8*)&out[(((size_t)(bb * NUM_HEADS + h) * DEPTH + d) << 12) + s0 + cm * 8] =
          *(const short8*)&T[SW128(n, cm)];
    }
  } else {
    const float scale = (z == 0) ? SCALE_Q : 1.0f;
#pragma unroll
    for (int fn = 0; fn < 4; ++fn) {
      int gn = nBase + nq + fn * 16 + lm;
      float bv = bias[gn];
      int h = gn >> 6, d = gn & 63;
#pragma unroll
      for (int fm = 0; fm < 4; ++fm) {
#pragma unroll
        for (int r = 0; r < 4; ++r) {
          int gm = mBase + mq + fm * 16 + lq * 4 + r;
          int bb = gm >> 12, s = gm & 4095;
          out[(((size_t)(bb * NUM_HEADS + h) * SEQ + s) << 6) + d] =
              f2bf((acc[fm][fn][r] + bv) * scale);
        }
      }
    }
  }
}

// ---------------- 128x64-tile output projection (bf16 X, fp32 W inline) -----
__global__ __launch_bounds__(256) void gemm_out_128x64(
    const unsigned short* __restrict__ X, // AO bf16 [8192][512]
    const float* __restrict__ W,          // fp32 [512][512]
    const float* __restrict__ bias,
    float* __restrict__ out) {
  __shared__ unsigned short As[128 * 64];
  __shared__ unsigned short Bs[64 * 64];
  const int t = threadIdx.x;
  const int w = t >> 6, l = t & 63, lq = l >> 4, lm = l & 15;
  const int mq = w * 32;
  const int mBase = blockIdx.x * 128, nBase = blockIdx.y * 64;
  float4v acc[2][4] = {};
  for (int kc = 0; kc < D_MODEL; kc += 64) {
    __syncthreads();
#pragma unroll
    for (int p = 0; p < 4; ++p) {
      int i = p * 256 + t, r = i >> 3, c = i & 7;
      *(short8*)&As[SW(r, c)] = *(const short8*)&X[(size_t)(mBase + r) * D_MODEL + kc + c * 8];
    }
#pragma unroll
    for (int p = 0; p < 2; ++p) {
      int i = p * 256 + t, r = i >> 3, c = i & 7;
      *(short8*)&Bs[SW(r, c)] = cvt8(&W[(size_t)(nBase + r) * D_MODEL + kc + c * 8]);
    }
    __syncthreads();
#pragma unroll
    for (int kk = 0; kk < 2; ++kk) {
      short8 av[2];
#pragma unroll
      for (int fm = 0; fm < 2; ++fm)
        av[fm] = *(const short8*)&As[SW(mq + fm * 16 + lm, kk * 4 + lq)];
#pragma unroll
      for (int fn = 0; fn < 4; ++fn) {
        short8 bv = *(const short8*)&Bs[SW(fn * 16 + lm, kk * 4 + lq)];
#pragma unroll
        for (int fm = 0; fm < 2; ++fm)
          acc[fm][fn] = __builtin_amdgcn_mfma_f32_16x16x32_bf16(av[fm], bv, acc[fm][fn], 0, 0, 0);
      }
    }
  }
#pragma unroll
  for (int fn = 0; fn < 4; ++fn) {
    int gn = nBase + fn * 16 + lm;
    float bv = bias[gn];
#pragma unroll
    for (int fm = 0; fm < 2; ++fm) {
#pragma unroll
      for (int r = 0; r < 4; ++r) {
        int gm = mBase + mq + fm * 16 + lq * 4 + r;
        out[(size_t)gm * D_MODEL + gn] = acc[fm][fn][r] + bv;
      }
    }
  }
}

// ---------------- fused attention -------------------------------------------
// Block = 4 waves x 32 q-rows = 128 q-rows of one (b,h). K-tiles of 64.
// Double-buffered LDS + register prefetch, ONE barrier per iter, 2x unrolled
// so all LDS addresses are loop-invariant. Q pre-scaled by 0.125*log2(e) ->
// p = exp2(S). Denominator via ones-MFMA on the matrix pipe.
__global__ __launch_bounds__(256) void attn(
    const unsigned short* __restrict__ Qh, // [bh][s][d] (pre-scaled)
    const unsigned short* __restrict__ Kh, // [bh][s][d]
    const unsigned short* __restrict__ Vt, // [bh][d][s]
    unsigned short* __restrict__ AO)       // [b][s][h*64+d] = [8192][512]
{
  __shared__ unsigned short Ksub[2][64 * 64]; // rows=k, cols=d (swizzled)
  __shared__ unsigned short Vsub[2][64 * 64]; // rows=d, cols=k (swizzled)
  __shared__ unsigned short Psub[128 * 64];   // rows=q(block-local), cols=k
  const int t = threadIdx.x;
  const int w = t >> 6; // wave 0..3
  const int l = t & 63, lq = l >> 4, lm = l & 15;
  const int bh = blockIdx.y;
  const size_t base = (size_t)bh * SEQ * DEPTH;
  const int qbase = blockIdx.x * 128 + w * 32;
  const unsigned short* __restrict__ Kp = Kh + base;
  const unsigned short* __restrict__ Vp = Vt + base;

  short8 qf[2][2];
#pragma unroll
  for (int qb = 0; qb < 2; ++qb)
#pragma unroll
    for (int kk = 0; kk < 2; ++kk)
      qf[qb][kk] = *(const short8*)&Qh[base + (size_t)(qbase + qb * 16 + lm) * DEPTH + kk * 32 + lq * 8];

  short8 ones;
#pragma unroll
  for (int j = 0; j < 8; ++j) ones[j] = (short)0x3F80; // bf16 1.0

  float4v oacc[2][4] = {};
  float4v sumacc[2] = {};
  short8 kreg[2], vreg[2];

  // preload tile 0
#pragma unroll
  for (int p = 0; p < 2; ++p) {
    int i = p * 256 + t, r = i >> 3, c = i & 7;
    kreg[p] = *(const short8*)&Kp[(size_t)r * DEPTH + c * 8];
    vreg[p] = *(const short8*)&Vp[(size_t)r * SEQ + c * 8];
  }
#pragma unroll
  for (int p = 0; p < 2; ++p) {
    int i = p * 256 + t, r = i >> 3, c = i & 7;
    *(short8*)&Ksub[0][SW(r, c)] = kreg[p];
    *(short8*)&Vsub[0][SW(r, c)] = vreg[p];
  }
  __syncthreads();

  auto step = [&](int cur, int tile, bool pf) {
    if (pf) {
      const int s0n = (tile + 1) * 64;
#pragma unroll
      for (int p = 0; p < 2; ++p) {
        int i = p * 256 + t, r = i >> 3, c = i & 7;
        kreg[p] = *(const short8*)&Kp[(size_t)(s0n + r) * DEPTH + c * 8];
        vreg[p] = *(const short8*)&Vp[(size_t)r * SEQ + s0n + c * 8];
      }
    }
    // S^T = K . Q^T : lane -> S[q = qb*16+lm][k = f*16 + lq*4 + r]
#pragma unroll
    for (int f = 0; f < 4; ++f) {
      float4v sacc[2] = {};
#pragma unroll
      for (int kk = 0; kk < 2; ++kk) {
        short8 a = *(const short8*)&Ksub[cur][SW(f * 16 + lm, kk * 4 + lq)];
        sacc[0] = __builtin_amdgcn_mfma_f32_16x16x32_bf16(a, qf[0][kk], sacc[0], 0, 0, 0);
        sacc[1] = __builtin_amdgcn_mfma_f32_16x16x32_bf16(a, qf[1][kk], sacc[1], 0, 0, 0);
      }
#pragma unroll
      for (int qb = 0; qb < 2; ++qb) {
        uint2 u;
        u.x = pk2f(__builtin_amdgcn_exp2f(sacc[qb][0]), __builtin_amdgcn_exp2f(sacc[qb][1]));
        u.y = pk2f(__builtin_amdgcn_exp2f(sacc[qb][2]), __builtin_amdgcn_exp2f(sacc[qb][3]));
        *(uint2*)&Psub[SW(w * 32 + qb * 16 + lm, 2 * f + (lq >> 1)) + (lq & 1) * 4] = u;
      }
    }
    // PV: O[q][d] += P[q][k] V^T[d][k]; denominator via B=ones MFMA.
#pragma unroll
    for (int kk = 0; kk < 2; ++kk) {
      short8 a0 = *(const short8*)&Psub[SW(w * 32 + lm, kk * 4 + lq)];
      short8 a1 = *(const short8*)&Psub[SW(w * 32 + 16 + lm, kk * 4 + lq)];
      sumacc[0] = __builtin_amdgcn_mfma_f32_16x16x32_bf16(a0, ones, sumacc[0], 0, 0, 0);
      sumacc[1] = __builtin_amdgcn_mfma_f32_16x16x32_bf16(a1, ones, sumacc[1], 0, 0, 0);
#pragma unroll
      for (int df = 0; df < 4; ++df) {
        short8 b = *(const short8*)&Vsub[cur][SW(df * 16 + lm, kk * 4 + lq)];
        oacc[0][df] = __builtin_amdgcn_mfma_f32_16x16x32_bf16(a0, b, oacc[0][df], 0, 0, 0);
        oacc[1][df] = __builtin_amdgcn_mfma_f32_16x16x32_bf16(a1, b, oacc[1][df], 0, 0, 0);
      }
    }
    if (pf) {
#pragma unroll
      for (int p = 0; p < 2; ++p) {
        int i = p * 256 + t, r = i >> 3, c = i & 7;
        *(short8*)&Ksub[cur ^ 1][SW(r, c)] = kreg[p];
        *(short8*)&Vsub[cur ^ 1][SW(r, c)] = vreg[p];
      }
    }
    __syncthreads();
  };

  for (int it = 0; it < 64; it += 2) {
    step(0, it, true);
    step(1, it + 1, it + 2 < 64);
  }

  // sumacc[qb][r] = rowsum(q = qbase + qb*16 + lq*4 + r) — same layout as oacc.
  const int bb = bh >> 3, h = bh & 7;
#pragma unroll
  for (int qb = 0; qb < 2; ++qb) {
#pragma unroll
    for (int r = 0; r < 4; ++r) {
      float rinv = 1.0f / sumacc[qb][r];
      int s = qbase + qb * 16 + lq * 4 + r;
#pragma unroll
      for (int df = 0; df < 4; ++df) {
        int d = df * 16 + lm;
        AO[((size_t)(bb * SEQ + s)) * D_MODEL + h * DEPTH + d] = f2bf(oacc[qb][df][r] * rinv);
      }
    }
  }
}

extern "C" void kernel_launch(void* const* d_in, const int* in_sizes, int n_in,
                              void* d_out, int out_size, void* d_ws, size_t ws_size,
                              hipStream_t stream) {
  const float* q = (const float*)d_in[0];
  const float* k = (const float*)d_in[1];
  const float* v = (const float*)d_in[2];
  const float* wq = (const float*)d_in[3];
  const float* bq = (const float*)d_in[4];
  const float* wk = (const float*)d_in[5];
  const float* bk = (const float*)d_in[6];
  const float* wv = (const float*)d_in[7];
  const float* bv = (const float*)d_in[8];
  const float* wo = (const float*)d_in[9];
  const float* bo = (const float*)d_in[10];

  const size_t HSD = (size_t)BATCH * NUM_HEADS * SEQ * DEPTH; // 4,194,304
  unsigned short* ws = (unsigned short*)d_ws;
  unsigned short* Qh = ws;
  unsigned short* Kh = Qh + HSD;
  unsigned short* Vt = Kh + HSD;
  unsigned short* AO = Vt + HSD; // total 33.6 MB — proven capacity

  QkvA qa;
  qa.X[0] = q; qa.X[1] = k; qa.X[2] = v;
  qa.W[0] = wq; qa.W[1] = wk; qa.W[2] = wv;
  qa.bias[0] = bq; qa.bias[1] = bk; qa.bias[2] = bv;
  qa.out[0] = Qh; qa.out[1] = Kh; qa.out[2] = Vt;
  gemm128_qkv<<<dim3(MROWS / 128, D_MODEL / 128, 3), 256, 0, stream>>>(qa);

  attn<<<dim3(SEQ / 128, BATCH * NUM_HEADS), 256, 0, stream>>>(Qh, Kh, Vt, AO);

  gemm_out_128x64<<<dim3(MROWS / 128, D_MODEL / 64), 256, 0, stream>>>(AO, wo, bo, (float*)d_out);
}

// Round 9
// 235.503 us; speedup vs baseline: 1.1663x; 1.1663x over previous
//
#include <hip/hip_runtime.h>

typedef __attribute__((ext_vector_type(8))) short short8;
typedef __attribute__((ext_vector_type(4))) float float4v;

#define D_MODEL 512
#define NUM_HEADS 8
#define DEPTH 64
#define SEQ 4096
#define BATCH 2
#define MROWS 8192
#define WSZ (D_MODEL * D_MODEL) // 262144
// 0.125 * log2(e): folded into Q projection so attn uses raw v_exp_f32 (exp2)
#define SCALE_Q 0.18033688011112043f

// swizzled short-index of 16B chunk c in row r of a 64-short-wide LDS tile
#define SW(r, c) (((r) * 64) + ((((c) ^ ((r) & 7))) * 8))

static __device__ __forceinline__ unsigned short f2bf(float f) {
  unsigned int u = __builtin_bit_cast(unsigned int, f);
  u += 0x7FFFu + ((u >> 16) & 1u); // RNE
  return (unsigned short)(u >> 16);
}
static __device__ __forceinline__ unsigned int pk2(float a, float b) {
  return (unsigned int)f2bf(a) | ((unsigned int)f2bf(b) << 16);
}
// fast pack: round-half-up (RNE except exact ties) + single v_perm_b32
static __device__ __forceinline__ unsigned int pk2f(float a, float b) {
  unsigned int ua = __builtin_bit_cast(unsigned int, a) + 0x8000u;
  unsigned int ub = __builtin_bit_cast(unsigned int, b) + 0x8000u;
  return __builtin_amdgcn_perm(ub, ua, 0x07060302u); // [b.3 b.2 a.3 a.2]
}
// convert 8 consecutive fp32 at p to short8 (RNE)
static __device__ __forceinline__ short8 cvt8(const float* p) {
  float4v f0 = *(const float4v*)p;
  float4v f1 = *(const float4v*)(p + 4);
  short8 s;
#pragma unroll
  for (int j = 0; j < 4; ++j) {
    s[j] = (short)f2bf(f0[j]);
    s[4 + j] = (short)f2bf(f1[j]);
  }
  return s;
}

// ---------------- weight conversion kernels ---------------------------------
__global__ __launch_bounds__(256) void cvt3(const float* __restrict__ w0,
                                            const float* __restrict__ w1,
                                            const float* __restrict__ w2,
                                            unsigned short* __restrict__ dst) {
  const float* srcs[3] = {w0, w1, w2};
  const int z = blockIdx.y;
  const float4v* s = (const float4v*)srcs[z];
  uint2* d = (uint2*)(dst + (size_t)z * WSZ);
  int i = blockIdx.x * 256 + threadIdx.x; // < WSZ/4
  float4v f = s[i];
  d[i] = make_uint2(pk2(f[0], f[1]), pk2(f[2], f[3]));
}
__global__ __launch_bounds__(256) void cvt1(const float* __restrict__ w,
                                            unsigned short* __restrict__ dst) {
  int i = blockIdx.x * 256 + threadIdx.x; // < WSZ/4
  float4v f = ((const float4v*)w)[i];
  ((uint2*)dst)[i] = make_uint2(pk2(f[0], f[1]), pk2(f[2], f[3]));
}

// ---------------- full-n QKV projection -------------------------------------
// Block: 64 m-rows x ALL 512 n. X (fp32) converted EXACTLY ONCE per element.
// W is preconverted bf16 (L2-hot, 2MB). z=0: Q (scaled); z=1: K; z=2: V->Vt.
struct QkvB {
  const float* X[3];
  const float* bias[3];
  unsigned short* out[3];
};
__global__ __launch_bounds__(256, 2) void qkv_fulln(QkvB a,
                                                    const unsigned short* __restrict__ Wall) {
  __shared__ unsigned short Xs[64 * 64];  // [m][k] swizzled
  __shared__ unsigned short Ws[512 * 64]; // [n][k] swizzled
  const int z = blockIdx.y;
  const float* __restrict__ X = a.X[z];
  const unsigned short* __restrict__ W = Wall + (size_t)z * WSZ;
  const float* __restrict__ bias = a.bias[z];
  unsigned short* __restrict__ out = a.out[z];
  const int t = threadIdx.x;
  const int w = t >> 6, l = t & 63, lq = l >> 4, lm = l & 15;
  const int mBase = blockIdx.x * 64;
  float4v acc[4][8] = {}; // [m-frag][n-frag], wave covers n in [w*128, w*128+128)

  for (int kc = 0; kc < D_MODEL; kc += 64) {
    __syncthreads();
#pragma unroll
    for (int p = 0; p < 2; ++p) { // X: 64 rows x 8 chunks
      int i = p * 256 + t, r = i >> 3, c = i & 7;
      *(short8*)&Xs[SW(r, c)] = cvt8(&X[(size_t)(mBase + r) * D_MODEL + kc + c * 8]);
    }
#pragma unroll 4
    for (int p = 0; p < 16; ++p) { // W: 512 rows x 8 chunks
      int i = p * 256 + t, r = i >> 3, c = i & 7;
      *(short8*)&Ws[SW(r, c)] = *(const short8*)&W[(size_t)r * D_MODEL + kc + c * 8];
    }
    __syncthreads();
#pragma unroll
    for (int kk = 0; kk < 2; ++kk) {
      short8 av[4];
#pragma unroll
      for (int fm = 0; fm < 4; ++fm)
        av[fm] = *(const short8*)&Xs[SW(fm * 16 + lm, kk * 4 + lq)];
#pragma unroll
      for (int fn = 0; fn < 8; ++fn) {
        short8 bv = *(const short8*)&Ws[SW(w * 128 + fn * 16 + lm, kk * 4 + lq)];
#pragma unroll
        for (int fm = 0; fm < 4; ++fm)
          acc[fm][fn] = __builtin_amdgcn_mfma_f32_16x16x32_bf16(av[fm], bv, acc[fm][fn], 0, 0, 0);
      }
    }
  }
  const int bb = mBase >> 12, s0 = mBase & 4095;
  if (z == 2) {
    // transpose to Vt [b][h][d][s] via LDS (reuse Ws as T[512 n][64 m])
    __syncthreads();
    unsigned short* T = Ws;
#pragma unroll
    for (int fn = 0; fn < 8; ++fn) {
      int n = w * 128 + fn * 16 + lm;
      float bv = bias[n];
#pragma unroll
      for (int fm = 0; fm < 4; ++fm) {
        int m0 = fm * 16 + lq * 4;
        uint2 u;
        u.x = pk2(acc[fm][fn][0] + bv, acc[fm][fn][1] + bv);
        u.y = pk2(acc[fm][fn][2] + bv, acc[fm][fn][3] + bv);
        *(uint2*)&T[SW(n, m0 >> 3) + (lq & 1) * 4] = u;
      }
    }
    __syncthreads();
#pragma unroll
    for (int p = 0; p < 16; ++p) { // 512 n-rows x 8 m-chunks
      int i = p * 256 + t, n = i >> 3, cm = i & 7;
      int h = n >> 6, d = n & 63;
      *(short8*)&out[(((size_t)(bb * NUM_HEADS + h) * DEPTH + d) << 12) + s0 + cm * 8] =
          *(const short8*)&T[SW(n, cm)];
    }
  } else {
    const float scale = (z == 0) ? SCALE_Q : 1.0f;
#pragma unroll
    for (int fn = 0; fn < 8; ++fn) {
      int gn = w * 128 + fn * 16 + lm;
      float bv = bias[gn];
      int h = gn >> 6, d = gn & 63;
#pragma unroll
      for (int fm = 0; fm < 4; ++fm) {
#pragma unroll
        for (int r = 0; r < 4; ++r) {
          int s = s0 + fm * 16 + lq * 4 + r;
          out[(((size_t)(bb * NUM_HEADS + h) * SEQ + s) << 6) + d] =
              f2bf((acc[fm][fn][r] + bv) * scale);
        }
      }
    }
  }
}

// ---------------- 128x64-tile output projection (bf16 X, bf16 W) ------------
__global__ __launch_bounds__(256) void gemm_out_128x64(
    const unsigned short* __restrict__ X, // AO bf16 [8192][512]
    const unsigned short* __restrict__ W, // bf16 [512][512]
    const float* __restrict__ bias,
    float* __restrict__ out) {
  __shared__ unsigned short As[128 * 64];
  __shared__ unsigned short Bs[64 * 64];
  const int t = threadIdx.x;
  const int w = t >> 6, l = t & 63, lq = l >> 4, lm = l & 15;
  const int mq = w * 32;
  const int mBase = blockIdx.x * 128, nBase = blockIdx.y * 64;
  float4v acc[2][4] = {};
  for (int kc = 0; kc < D_MODEL; kc += 64) {
    __syncthreads();
#pragma unroll
    for (int p = 0; p < 4; ++p) {
      int i = p * 256 + t, r = i >> 3, c = i & 7;
      *(short8*)&As[SW(r, c)] = *(const short8*)&X[(size_t)(mBase + r) * D_MODEL + kc + c * 8];
    }
#pragma unroll
    for (int p = 0; p < 2; ++p) {
      int i = p * 256 + t, r = i >> 3, c = i & 7;
      *(short8*)&Bs[SW(r, c)] = *(const short8*)&W[(size_t)(nBase + r) * D_MODEL + kc + c * 8];
    }
    __syncthreads();
#pragma unroll
    for (int kk = 0; kk < 2; ++kk) {
      short8 av[2];
#pragma unroll
      for (int fm = 0; fm < 2; ++fm)
        av[fm] = *(const short8*)&As[SW(mq + fm * 16 + lm, kk * 4 + lq)];
#pragma unroll
      for (int fn = 0; fn < 4; ++fn) {
        short8 bv = *(const short8*)&Bs[SW(fn * 16 + lm, kk * 4 + lq)];
#pragma unroll
        for (int fm = 0; fm < 2; ++fm)
          acc[fm][fn] = __builtin_amdgcn_mfma_f32_16x16x32_bf16(av[fm], bv, acc[fm][fn], 0, 0, 0);
      }
    }
  }
#pragma unroll
  for (int fn = 0; fn < 4; ++fn) {
    int gn = nBase + fn * 16 + lm;
    float bv = bias[gn];
#pragma unroll
    for (int fm = 0; fm < 2; ++fm) {
#pragma unroll
      for (int r = 0; r < 4; ++r) {
        int gm = mBase + mq + fm * 16 + lq * 4 + r;
        out[(size_t)gm * D_MODEL + gn] = acc[fm][fn][r] + bv;
      }
    }
  }
}

// ---------------- fused attention (unchanged from R8) -----------------------
__global__ __launch_bounds__(256) void attn(
    const unsigned short* __restrict__ Qh, // [bh][s][d] (pre-scaled)
    const unsigned short* __restrict__ Kh, // [bh][s][d]
    const unsigned short* __restrict__ Vt, // [bh][d][s]
    unsigned short* __restrict__ AO)       // [b][s][h*64+d] = [8192][512]
{
  __shared__ unsigned short Ksub[2][64 * 64];
  __shared__ unsigned short Vsub[2][64 * 64];
  __shared__ unsigned short Psub[128 * 64];
  const int t = threadIdx.x;
  const int w = t >> 6;
  const int l = t & 63, lq = l >> 4, lm = l & 15;
  const int bh = blockIdx.y;
  const size_t base = (size_t)bh * SEQ * DEPTH;
  const int qbase = blockIdx.x * 128 + w * 32;
  const unsigned short* __restrict__ Kp = Kh + base;
  const unsigned short* __restrict__ Vp = Vt + base;

  short8 qf[2][2];
#pragma unroll
  for (int qb = 0; qb < 2; ++qb)
#pragma unroll
    for (int kk = 0; kk < 2; ++kk)
      qf[qb][kk] = *(const short8*)&Qh[base + (size_t)(qbase + qb * 16 + lm) * DEPTH + kk * 32 + lq * 8];

  short8 ones;
#pragma unroll
  for (int j = 0; j < 8; ++j) ones[j] = (short)0x3F80;

  float4v oacc[2][4] = {};
  float4v sumacc[2] = {};
  short8 kreg[2], vreg[2];

#pragma unroll
  for (int p = 0; p < 2; ++p) {
    int i = p * 256 + t, r = i >> 3, c = i & 7;
    kreg[p] = *(const short8*)&Kp[(size_t)r * DEPTH + c * 8];
    vreg[p] = *(const short8*)&Vp[(size_t)r * SEQ + c * 8];
  }
#pragma unroll
  for (int p = 0; p < 2; ++p) {
    int i = p * 256 + t, r = i >> 3, c = i & 7;
    *(short8*)&Ksub[0][SW(r, c)] = kreg[p];
    *(short8*)&Vsub[0][SW(r, c)] = vreg[p];
  }
  __syncthreads();

  auto step = [&](int cur, int tile, bool pf) {
    if (pf) {
      const int s0n = (tile + 1) * 64;
#pragma unroll
      for (int p = 0; p < 2; ++p) {
        int i = p * 256 + t, r = i >> 3, c = i & 7;
        kreg[p] = *(const short8*)&Kp[(size_t)(s0n + r) * DEPTH + c * 8];
        vreg[p] = *(const short8*)&Vp[(size_t)r * SEQ + s0n + c * 8];
      }
    }
#pragma unroll
    for (int f = 0; f < 4; ++f) {
      float4v sacc[2] = {};
#pragma unroll
      for (int kk = 0; kk < 2; ++kk) {
        short8 a = *(const short8*)&Ksub[cur][SW(f * 16 + lm, kk * 4 + lq)];
        sacc[0] = __builtin_amdgcn_mfma_f32_16x16x32_bf16(a, qf[0][kk], sacc[0], 0, 0, 0);
        sacc[1] = __builtin_amdgcn_mfma_f32_16x16x32_bf16(a, qf[1][kk], sacc[1], 0, 0, 0);
      }
#pragma unroll
      for (int qb = 0; qb < 2; ++qb) {
        uint2 u;
        u.x = pk2f(__builtin_amdgcn_exp2f(sacc[qb][0]), __builtin_amdgcn_exp2f(sacc[qb][1]));
        u.y = pk2f(__builtin_amdgcn_exp2f(sacc[qb][2]), __builtin_amdgcn_exp2f(sacc[qb][3]));
        *(uint2*)&Psub[SW(w * 32 + qb * 16 + lm, 2 * f + (lq >> 1)) + (lq & 1) * 4] = u;
      }
    }
#pragma unroll
    for (int kk = 0; kk < 2; ++kk) {
      short8 a0 = *(const short8*)&Psub[SW(w * 32 + lm, kk * 4 + lq)];
      short8 a1 = *(const short8*)&Psub[SW(w * 32 + 16 + lm, kk * 4 + lq)];
      sumacc[0] = __builtin_amdgcn_mfma_f32_16x16x32_bf16(a0, ones, sumacc[0], 0, 0, 0);
      sumacc[1] = __builtin_amdgcn_mfma_f32_16x16x32_bf16(a1, ones, sumacc[1], 0, 0, 0);
#pragma unroll
      for (int df = 0; df < 4; ++df) {
        short8 b = *(const short8*)&Vsub[cur][SW(df * 16 + lm, kk * 4 + lq)];
        oacc[0][df] = __builtin_amdgcn_mfma_f32_16x16x32_bf16(a0, b, oacc[0][df], 0, 0, 0);
        oacc[1][df] = __builtin_amdgcn_mfma_f32_16x16x32_bf16(a1, b, oacc[1][df], 0, 0, 0);
      }
    }
    if (pf) {
#pragma unroll
      for (int p = 0; p < 2; ++p) {
        int i = p * 256 + t, r = i >> 3, c = i & 7;
        *(short8*)&Ksub[cur ^ 1][SW(r, c)] = kreg[p];
        *(short8*)&Vsub[cur ^ 1][SW(r, c)] = vreg[p];
      }
    }
    __syncthreads();
  };

  for (int it = 0; it < 64; it += 2) {
    step(0, it, true);
    step(1, it + 1, it + 2 < 64);
  }

  const int bb = bh >> 3, h = bh & 7;
#pragma unroll
  for (int qb = 0; qb < 2; ++qb) {
#pragma unroll
    for (int r = 0; r < 4; ++r) {
      float rinv = 1.0f / sumacc[qb][r];
      int s = qbase + qb * 16 + lq * 4 + r;
#pragma unroll
      for (int df = 0; df < 4; ++df) {
        int d = df * 16 + lm;
        AO[((size_t)(bb * SEQ + s)) * D_MODEL + h * DEPTH + d] = f2bf(oacc[qb][df][r] * rinv);
      }
    }
  }
}

extern "C" void kernel_launch(void* const* d_in, const int* in_sizes, int n_in,
                              void* d_out, int out_size, void* d_ws, size_t ws_size,
                              hipStream_t stream) {
  const float* q = (const float*)d_in[0];
  const float* k = (const float*)d_in[1];
  const float* v = (const float*)d_in[2];
  const float* wq = (const float*)d_in[3];
  const float* bq = (const float*)d_in[4];
  const float* wk = (const float*)d_in[5];
  const float* bk = (const float*)d_in[6];
  const float* wv = (const float*)d_in[7];
  const float* bv = (const float*)d_in[8];
  const float* wo = (const float*)d_in[9];
  const float* bo = (const float*)d_in[10];

  const size_t HSD = (size_t)BATCH * NUM_HEADS * SEQ * DEPTH; // 4,194,304
  unsigned short* ws = (unsigned short*)d_ws;
  unsigned short* Qh = ws;
  unsigned short* Kh = Qh + HSD;
  unsigned short* Vt = Kh + HSD;
  unsigned short* AO = Vt + HSD; // total 33.6 MB — proven capacity
  // Wqkv (bf16, 1.5 MB) lives in the AO region: consumed by qkv_fulln BEFORE
  // attn overwrites AO. Wo (bf16, 0.5 MB) goes into Vt AFTER attn is done.
  unsigned short* Wqkv = AO;
  unsigned short* Wo = Vt;

  cvt3<<<dim3(WSZ / 4 / 256, 3), 256, 0, stream>>>(wq, wk, wv, Wqkv);

  QkvB qa;
  qa.X[0] = q; qa.X[1] = k; qa.X[2] = v;
  qa.bias[0] = bq; qa.bias[1] = bk; qa.bias[2] = bv;
  qa.out[0] = Qh; qa.out[1] = Kh; qa.out[2] = Vt;
  qkv_fulln<<<dim3(MROWS / 64, 3), 256, 0, stream>>>(qa, Wqkv);

  attn<<<dim3(SEQ / 128, BATCH * NUM_HEADS), 256, 0, stream>>>(Qh, Kh, Vt, AO);

  cvt1<<<WSZ / 4 / 256, 256, 0, stream>>>(wo, Wo);

  gemm_out_128x64<<<dim3(MROWS / 128, D_MODEL / 64), 256, 0, stream>>>(AO, Wo, bo, (float*)d_out);
}